// Round 1
// baseline (5441.193 us; speedup 1.0000x reference)
//
#include <hip/hip_runtime.h>
#include <math.h>

#define HD    1024
#define BATCH 4096
#define VOC   64
#define MSGL  16
#define KA    2048   // A width = [relu(x) | h]
#define NG    4096   // gates width = 4H

typedef _Float16 f16;
typedef _Float16 f16x8 __attribute__((ext_vector_type(8)));
typedef _Float16 f16x4 __attribute__((ext_vector_type(4)));
typedef float    f32x4 __attribute__((ext_vector_type(4)));

__device__ __forceinline__ void splt(float v, f16& hi, f16& lo) {
    f16 h = (f16)v;
    hi = h;
    lo = (f16)(v - (float)h);
}

__device__ __forceinline__ float sigm(float x) { return 1.0f / (1.0f + expf(-x)); }

__device__ __forceinline__ void async16(void* lds, const void* g) {
    __builtin_amdgcn_global_load_lds(
        (const __attribute__((address_space(1))) void*)g,
        (__attribute__((address_space(3))) void*)lds, 16, 0, 0);
}

// ---------------- gates GEMM: [4096,2048] x [4096,2048]^T -> [4096,4096] ----
// fp16 hi/lo split, 3-pass MFMA, fp32 accumulate. 128x128 tile, 4 waves.
__global__ __launch_bounds__(256) void gemm_gates(
    const f16* __restrict__ Ahi, const f16* __restrict__ Alo,
    const f16* __restrict__ Whi, const f16* __restrict__ Wlo,
    float* __restrict__ gates)
{
    __shared__ f16 sAh[128 * 32], sAl[128 * 32], sBh[128 * 32], sBl[128 * 32];
    const int tid  = threadIdx.x;
    const int lane = tid & 63;
    const int wv   = tid >> 6;
    const int wm   = wv >> 1;
    const int wn   = wv & 1;
    const int bm   = blockIdx.y * 128;
    const int bn   = blockIdx.x * 128;

    const int srow = tid >> 2;          // staging row (0..63), +64 for round 1
    const int scol = (tid & 3) * 8;     // staging k-offset in elements

    f32x4 zero = {0.f, 0.f, 0.f, 0.f};
    f32x4 acc[4][4];
#pragma unroll
    for (int i = 0; i < 4; ++i)
#pragma unroll
        for (int j = 0; j < 4; ++j) acc[i][j] = zero;

    for (int k0 = 0; k0 < KA; k0 += 32) {
        __syncthreads();
#pragma unroll
        for (int r = 0; r < 2; ++r) {
            const int row = srow + r * 64;
            const size_t ga = (size_t)(bm + row) * KA + k0 + scol;
            const size_t gb = (size_t)(bn + row) * KA + k0 + scol;
            const int lo = row * 32 + scol;
            async16(&sAh[lo], Ahi + ga);
            async16(&sAl[lo], Alo + ga);
            async16(&sBh[lo], Whi + gb);
            async16(&sBl[lo], Wlo + gb);
        }
        __syncthreads();

        f16x8 fah[4], fal[4], fbh[4], fbl[4];
        const int ks = (lane >> 4) * 8;
#pragma unroll
        for (int i = 0; i < 4; ++i) {
            const int ar = wm * 64 + i * 16 + (lane & 15);
            fah[i] = *(const f16x8*)&sAh[ar * 32 + ks];
            fal[i] = *(const f16x8*)&sAl[ar * 32 + ks];
            const int br = wn * 64 + i * 16 + (lane & 15);
            fbh[i] = *(const f16x8*)&sBh[br * 32 + ks];
            fbl[i] = *(const f16x8*)&sBl[br * 32 + ks];
        }
#pragma unroll
        for (int i = 0; i < 4; ++i)
#pragma unroll
            for (int j = 0; j < 4; ++j) {
                acc[i][j] = __builtin_amdgcn_mfma_f32_16x16x32_f16(fah[i], fbh[j], acc[i][j], 0, 0, 0);
                acc[i][j] = __builtin_amdgcn_mfma_f32_16x16x32_f16(fah[i], fbl[j], acc[i][j], 0, 0, 0);
                acc[i][j] = __builtin_amdgcn_mfma_f32_16x16x32_f16(fal[i], fbh[j], acc[i][j], 0, 0, 0);
            }
    }

    const int q  = lane >> 4;
    const int cn = lane & 15;
#pragma unroll
    for (int i = 0; i < 4; ++i)
#pragma unroll
        for (int j = 0; j < 4; ++j)
#pragma unroll
            for (int rg = 0; rg < 4; ++rg) {
                const int row = bm + wm * 64 + i * 16 + q * 4 + rg;
                const int col = bn + wn * 64 + j * 16 + cn;
                gates[(size_t)row * NG + col] = acc[i][j][rg];
            }
}

// ---------------- LSTM cell elementwise -------------------------------------
__global__ __launch_bounds__(256) void lstm_cell(
    const float* __restrict__ gates,
    const float* __restrict__ b_ih, const float* __restrict__ b_hh,
    float* __restrict__ cbuf, float* __restrict__ hbuf,
    f16* __restrict__ Ahi, f16* __restrict__ Alo)
{
    const int idx = (blockIdx.x * 256 + threadIdx.x) * 4;   // over B*H
    const int b = idx >> 10;
    const int j = idx & 1023;
    const size_t gb = (size_t)b * NG + j;

    const float4 gi = *(const float4*)&gates[gb];
    const float4 gf = *(const float4*)&gates[gb + 1024];
    const float4 gg = *(const float4*)&gates[gb + 2048];
    const float4 go = *(const float4*)&gates[gb + 3072];
    const float4 b1i = *(const float4*)&b_ih[j];
    const float4 b1f = *(const float4*)&b_ih[j + 1024];
    const float4 b1g = *(const float4*)&b_ih[j + 2048];
    const float4 b1o = *(const float4*)&b_ih[j + 3072];
    const float4 b2i = *(const float4*)&b_hh[j];
    const float4 b2f = *(const float4*)&b_hh[j + 1024];
    const float4 b2g = *(const float4*)&b_hh[j + 2048];
    const float4 b2o = *(const float4*)&b_hh[j + 3072];
    const float4 cv  = *(const float4*)&cbuf[idx];

    float iv[4] = {gi.x + b1i.x + b2i.x, gi.y + b1i.y + b2i.y, gi.z + b1i.z + b2i.z, gi.w + b1i.w + b2i.w};
    float fv[4] = {gf.x + b1f.x + b2f.x, gf.y + b1f.y + b2f.y, gf.z + b1f.z + b2f.z, gf.w + b1f.w + b2f.w};
    float gv[4] = {gg.x + b1g.x + b2g.x, gg.y + b1g.y + b2g.y, gg.z + b1g.z + b2g.z, gg.w + b1g.w + b2g.w};
    float ov[4] = {go.x + b1o.x + b2o.x, go.y + b1o.y + b2o.y, go.z + b1o.z + b2o.z, go.w + b1o.w + b2o.w};
    float cold[4] = {cv.x, cv.y, cv.z, cv.w};

    float cn_[4], hn[4];
#pragma unroll
    for (int c = 0; c < 4; ++c) {
        const float I = sigm(iv[c]);
        const float F = sigm(fv[c]);
        const float G = tanhf(gv[c]);
        const float O = sigm(ov[c]);
        const float cc = F * cold[c] + I * G;
        cn_[c] = cc;
        hn[c]  = O * tanhf(cc);
    }
    *(float4*)&cbuf[idx] = make_float4(cn_[0], cn_[1], cn_[2], cn_[3]);
    *(float4*)&hbuf[idx] = make_float4(hn[0], hn[1], hn[2], hn[3]);

    f16x4 vh, vl;
#pragma unroll
    for (int c = 0; c < 4; ++c) {
        f16 hi_, lo_;
        splt(hn[c], hi_, lo_);
        vh[c] = hi_; vl[c] = lo_;
    }
    *(f16x4*)&Ahi[(size_t)b * KA + HD + j] = vh;
    *(f16x4*)&Alo[(size_t)b * KA + HD + j] = vl;
}

// ---------------- logits + softmax + argmax + outputs + x-gather ------------
// one wave handles 8 batch rows; lane == vocab index (V=64)
__global__ __launch_bounds__(256) void logits_step(
    const float* __restrict__ hbuf, const float* __restrict__ W_out,
    const float* __restrict__ b_out, const float* __restrict__ emb,
    f16* __restrict__ Ahi, f16* __restrict__ Alo,
    float* __restrict__ omsg, float* __restrict__ odig,
    float* __restrict__ ologp, int t)
{
    const int lane  = threadIdx.x & 63;
    const int wv    = threadIdx.x >> 6;
    const int rbase = blockIdx.x * 32 + wv * 8;

    float acc[8] = {0.f, 0.f, 0.f, 0.f, 0.f, 0.f, 0.f, 0.f};
    const float* wrow = W_out + (size_t)lane * HD;
    for (int k = 0; k < HD; k += 4) {
        const float4 wvv = *(const float4*)&wrow[k];
#pragma unroll
        for (int r = 0; r < 8; ++r) {
            const float4 hv = *(const float4*)&hbuf[(size_t)(rbase + r) * HD + k];
            acc[r] += wvv.x * hv.x + wvv.y * hv.y + wvv.z * hv.z + wvv.w * hv.w;
        }
    }
    const float bo = b_out[lane];

    for (int r = 0; r < 8; ++r) {
        const int row = rbase + r;
        const float lg = acc[r] + bo;

        float m = lg; int am = lane;
#pragma unroll
        for (int d = 1; d < 64; d <<= 1) {
            const float om = __shfl_xor(m, d);
            const int   oa = __shfl_xor(am, d);
            if (om > m || (om == m && oa < am)) { m = om; am = oa; }
        }
        float s = expf(lg - m);
#pragma unroll
        for (int d = 1; d < 64; d <<= 1) s += __shfl_xor(s, d);

        odig[(size_t)row * VOC + lane] = lg;
        omsg[(size_t)row * VOC + lane] = (lane == am) ? 1.0f : 0.0f;
        if (lane == 0) {
            const float prev = (t == 0) ? 0.0f : ologp[row];
            ologp[row] = prev - logf(s);   // log(probs[argmax]) = -log(sum exp(l-m))
        }

        // x_next = relu(emb[argmax]) split into A (cols 0..1023)
        const float* er = emb + (size_t)am * HD;
#pragma unroll
        for (int c = 0; c < 4; ++c) {
            const int k = (c * 64 + lane) * 4;
            float4 ev = *(const float4*)&er[k];
            f16x4 vh, vl; f16 hi_, lo_;
            float e;
            e = fmaxf(ev.x, 0.f); splt(e, hi_, lo_); vh[0] = hi_; vl[0] = lo_;
            e = fmaxf(ev.y, 0.f); splt(e, hi_, lo_); vh[1] = hi_; vl[1] = lo_;
            e = fmaxf(ev.z, 0.f); splt(e, hi_, lo_); vh[2] = hi_; vl[2] = lo_;
            e = fmaxf(ev.w, 0.f); splt(e, hi_, lo_); vh[3] = hi_; vl[3] = lo_;
            *(f16x4*)&Ahi[(size_t)row * KA + k] = vh;
            *(f16x4*)&Alo[(size_t)row * KA + k] = vl;
        }
    }
}

// ---------------- prep kernels ----------------------------------------------
__global__ __launch_bounds__(256) void prep_w(
    const float* __restrict__ W_ih, const float* __restrict__ W_hh,
    f16* __restrict__ Whi, f16* __restrict__ Wlo)
{
    const int idx = (blockIdx.x * 256 + threadIdx.x) * 4;   // over NG*KA
    const int n = idx >> 11;
    const int k = idx & 2047;
    const float* src = (k < HD) ? &W_ih[(size_t)n * HD + k] : &W_hh[(size_t)n * HD + (k - HD)];
    const float4 v = *(const float4*)src;
    f16x4 vh, vl; f16 hi_, lo_;
    splt(v.x, hi_, lo_); vh[0] = hi_; vl[0] = lo_;
    splt(v.y, hi_, lo_); vh[1] = hi_; vl[1] = lo_;
    splt(v.z, hi_, lo_); vh[2] = hi_; vl[2] = lo_;
    splt(v.w, hi_, lo_); vh[3] = hi_; vl[3] = lo_;
    *(f16x4*)&Whi[idx] = vh;
    *(f16x4*)&Wlo[idx] = vl;
}

__global__ __launch_bounds__(256) void prep_a(
    const float* __restrict__ ench, const float* __restrict__ x0,
    f16* __restrict__ Ahi, f16* __restrict__ Alo)
{
    const int idx = (blockIdx.x * 256 + threadIdx.x) * 4;   // over BATCH*KA
    const int b = idx >> 11;
    const int k = idx & 2047;
    float4 v;
    if (k < HD) {
        v = *(const float4*)&x0[k];   // broadcast row, relu applied
        v.x = fmaxf(v.x, 0.f); v.y = fmaxf(v.y, 0.f);
        v.z = fmaxf(v.z, 0.f); v.w = fmaxf(v.w, 0.f);
    } else {
        v = *(const float4*)&ench[(size_t)b * HD + (k - HD)];
    }
    f16x4 vh, vl; f16 hi_, lo_;
    splt(v.x, hi_, lo_); vh[0] = hi_; vl[0] = lo_;
    splt(v.y, hi_, lo_); vh[1] = hi_; vl[1] = lo_;
    splt(v.z, hi_, lo_); vh[2] = hi_; vl[2] = lo_;
    splt(v.w, hi_, lo_); vh[3] = hi_; vl[3] = lo_;
    *(f16x4*)&Ahi[idx] = vh;
    *(f16x4*)&Alo[idx] = vl;
}

__global__ __launch_bounds__(256) void prep_c(
    const float* __restrict__ encc, float* __restrict__ cbuf)
{
    const int idx = (blockIdx.x * 256 + threadIdx.x) * 4;
    *(float4*)&cbuf[idx] = *(const float4*)&encc[idx];
}

__global__ __launch_bounds__(256) void prep_mask(float* __restrict__ mask)
{
    mask[blockIdx.x * 256 + threadIdx.x] = 1.0f;
}

// ---------------- launch ----------------------------------------------------
extern "C" void kernel_launch(void* const* d_in, const int* in_sizes, int n_in,
                              void* d_out, int out_size, void* d_ws, size_t ws_size,
                              hipStream_t stream)
{
    const float* ench  = (const float*)d_in[0];
    const float* encc  = (const float*)d_in[1];
    const float* W_ih  = (const float*)d_in[2];
    const float* W_hh  = (const float*)d_in[3];
    const float* b_ih  = (const float*)d_in[4];
    const float* b_hh  = (const float*)d_in[5];
    const float* W_out = (const float*)d_in[6];
    const float* b_out = (const float*)d_in[7];
    const float* x0    = (const float*)d_in[8];
    const float* emb   = (const float*)d_in[9];
    float* out = (float*)d_out;

    char* ws = (char*)d_ws;
    f16*   Ahi   = (f16*)(ws);
    f16*   Alo   = (f16*)(ws + ((size_t)16 << 20));
    f16*   Whi   = (f16*)(ws + ((size_t)32 << 20));
    f16*   Wlo   = (f16*)(ws + ((size_t)48 << 20));
    float* gates = (float*)(ws + ((size_t)64 << 20));
    float* cbuf  = (float*)(ws + ((size_t)128 << 20));
    float* hbuf  = (float*)(ws + ((size_t)144 << 20));

    float* out_msg0 = out;                                        // [L,B,V]
    float* out_mask = out + (size_t)MSGL * BATCH * VOC;           // [L,1,B]
    float* out_dig0 = out_mask + (size_t)MSGL * BATCH;            // [L,B,V]
    float* out_logp = out_dig0 + (size_t)MSGL * BATCH * VOC;      // [B]

    prep_w<<<8192, 256, 0, stream>>>(W_ih, W_hh, Whi, Wlo);
    prep_a<<<8192, 256, 0, stream>>>(ench, x0, Ahi, Alo);
    prep_c<<<4096, 256, 0, stream>>>(encc, cbuf);
    prep_mask<<<256, 256, 0, stream>>>(out_mask);

    for (int t = 0; t < MSGL; ++t) {
        gemm_gates<<<dim3(32, 32), 256, 0, stream>>>(Ahi, Alo, Whi, Wlo, gates);
        lstm_cell<<<4096, 256, 0, stream>>>(gates, b_ih, b_hh, cbuf, hbuf, Ahi, Alo);
        logits_step<<<128, 256, 0, stream>>>(
            hbuf, W_out, b_out, emb, Ahi, Alo,
            out_msg0 + (size_t)t * BATCH * VOC,
            out_dig0 + (size_t)t * BATCH * VOC,
            out_logp, t);
    }
}

// Round 2
// 3989.088 us; speedup vs baseline: 1.3640x; 1.3640x over previous
//
#include <hip/hip_runtime.h>
#include <math.h>

#define HD    1024
#define BATCH 4096
#define VOC   64
#define MSGL  16
#define KA    2048   // A width = [relu(x) | h]
#define NG    4096   // gates width = 4H

typedef _Float16 f16;
typedef _Float16 f16x8 __attribute__((ext_vector_type(8)));
typedef _Float16 f16x4 __attribute__((ext_vector_type(4)));
typedef float    f32x4 __attribute__((ext_vector_type(4)));

__device__ __forceinline__ void splt(float v, f16& hi, f16& lo) {
    f16 h = (f16)v;
    hi = h;
    lo = (f16)(v - (float)h);
}

__device__ __forceinline__ float sigm(float x) { return 1.0f / (1.0f + expf(-x)); }

__device__ __forceinline__ void async16(void* lds, const void* g) {
    __builtin_amdgcn_global_load_lds(
        (const __attribute__((address_space(1))) void*)g,
        (__attribute__((address_space(3))) void*)lds, 16, 0, 0);
}

// ---------------- fused gates GEMM + LSTM cell ------------------------------
// A[4096,2048] x Wr[4096,2048]^T with Wr rows permuted so each 128-col tile
// holds complete (i,f,g,o) quadruples:  n' = bx*128 + jh*64 + g*16 + (jj&15),
// j = bx*32 + jh*16 + (jj&15),  orig n = g*1024 + j.
// fp16 hi/lo split, 3-pass MFMA, fp32 accumulate. 128x128 tile, 4 waves (2x2).
// Epilogue: bias + LSTM cell in-register; writes cbuf/hbuf and next-step A.
__global__ __launch_bounds__(256) void gemm_fused(
    const f16* __restrict__ Ahi, const f16* __restrict__ Alo,
    const f16* __restrict__ Whi, const f16* __restrict__ Wlo,
    const float* __restrict__ bR,
    float* __restrict__ cbuf, float* __restrict__ hbuf,
    f16* __restrict__ AhiN, f16* __restrict__ AloN)
{
    __shared__ f16 sAh[128 * 32], sAl[128 * 32], sBh[128 * 32], sBl[128 * 32];
    const int tid  = threadIdx.x;
    const int lane = tid & 63;
    const int wv   = tid >> 6;
    const int wm   = wv >> 1;
    const int wn   = wv & 1;

    // XCD-aware bijective swizzle (1024 blocks, 1024 % 8 == 0)
    const int linear = blockIdx.y * 32 + blockIdx.x;
    const int swz    = (linear & 7) * 128 + (linear >> 3);
    const int by     = swz >> 5;       // M tile
    const int bx     = swz & 31;       // N tile
    const int bm     = by * 128;       // batch-row offset
    const int bnp    = bx * 128;       // n' offset (permuted gate space)

    const int srow = tid >> 2;          // staging row (0..63), +64 for round 1
    const int scol = (tid & 3) * 8;     // staging k-offset in elements

    f32x4 zero = {0.f, 0.f, 0.f, 0.f};
    f32x4 acc[4][4];
#pragma unroll
    for (int i = 0; i < 4; ++i)
#pragma unroll
        for (int j = 0; j < 4; ++j) acc[i][j] = zero;

    for (int k0 = 0; k0 < KA; k0 += 32) {
        __syncthreads();
#pragma unroll
        for (int r = 0; r < 2; ++r) {
            const int row = srow + r * 64;
            const size_t ga = (size_t)(bm + row) * KA + k0 + scol;
            const size_t gb = (size_t)(bnp + row) * KA + k0 + scol;
            const int lo = row * 32 + scol;
            async16(&sAh[lo], Ahi + ga);
            async16(&sAl[lo], Alo + ga);
            async16(&sBh[lo], Whi + gb);
            async16(&sBl[lo], Wlo + gb);
        }
        __syncthreads();

        f16x8 fah[4], fal[4], fbh[4], fbl[4];
        const int ks = (lane >> 4) * 8;
#pragma unroll
        for (int i = 0; i < 4; ++i) {
            const int ar = wm * 64 + i * 16 + (lane & 15);
            fah[i] = *(const f16x8*)&sAh[ar * 32 + ks];
            fal[i] = *(const f16x8*)&sAl[ar * 32 + ks];
            const int br = wn * 64 + i * 16 + (lane & 15);
            fbh[i] = *(const f16x8*)&sBh[br * 32 + ks];
            fbl[i] = *(const f16x8*)&sBl[br * 32 + ks];
        }
#pragma unroll
        for (int i = 0; i < 4; ++i)
#pragma unroll
            for (int j = 0; j < 4; ++j) {
                acc[i][j] = __builtin_amdgcn_mfma_f32_16x16x32_f16(fah[i], fbh[j], acc[i][j], 0, 0, 0);
                acc[i][j] = __builtin_amdgcn_mfma_f32_16x16x32_f16(fah[i], fbl[j], acc[i][j], 0, 0, 0);
                acc[i][j] = __builtin_amdgcn_mfma_f32_16x16x32_f16(fal[i], fbh[j], acc[i][j], 0, 0, 0);
            }
    }

    // ---- epilogue: LSTM cell ----
    // lane's fragment g (=0..3) is gate g for j = bx*32 + wn*16 + cn
    const int q  = lane >> 4;
    const int cn = lane & 15;
    const int jglob = bx * 32 + wn * 16 + cn;

    float bias[4];
#pragma unroll
    for (int g = 0; g < 4; ++g) bias[g] = bR[bnp + wn * 64 + g * 16 + cn];

#pragma unroll
    for (int i = 0; i < 4; ++i) {
#pragma unroll
        for (int rg = 0; rg < 4; ++rg) {
            const int row = bm + wm * 64 + i * 16 + q * 4 + rg;
            const float iv = acc[i][0][rg] + bias[0];
            const float fv = acc[i][1][rg] + bias[1];
            const float gv = acc[i][2][rg] + bias[2];
            const float ov = acc[i][3][rg] + bias[3];
            const size_t cidx = (size_t)row * HD + jglob;
            const float cold = cbuf[cidx];
            const float I = sigm(iv);
            const float F = sigm(fv);
            const float G = tanhf(gv);
            const float O = sigm(ov);
            const float cc = F * cold + I * G;
            const float hh = O * tanhf(cc);
            cbuf[cidx] = cc;
            hbuf[cidx] = hh;
            f16 hi_, lo_;
            splt(hh, hi_, lo_);
            AhiN[(size_t)row * KA + HD + jglob] = hi_;
            AloN[(size_t)row * KA + HD + jglob] = lo_;
        }
    }
}

// ---------------- logits + softmax + argmax + outputs + x-gather ------------
// 4 waves/block, 2 rows per wave; lane == vocab index (V=64)
__global__ __launch_bounds__(256) void logits_step(
    const float* __restrict__ hbuf, const float* __restrict__ W_outT,
    const float* __restrict__ b_out,
    const f16* __restrict__ embHi, const f16* __restrict__ embLo,
    f16* __restrict__ AhiN, f16* __restrict__ AloN,
    float* __restrict__ omsg, float* __restrict__ odig,
    float* __restrict__ ologp, int t)
{
    const int lane = threadIdx.x & 63;
    const int wv   = threadIdx.x >> 6;
    const int r0   = blockIdx.x * 8 + wv * 2;

    float a0 = 0.f, a1 = 0.f;
    const float* h0 = hbuf + (size_t)r0 * HD;
    const float* h1 = h0 + HD;
    for (int k = 0; k < HD; k += 4) {
        const float w0 = W_outT[(k + 0) * 64 + lane];
        const float w1 = W_outT[(k + 1) * 64 + lane];
        const float w2 = W_outT[(k + 2) * 64 + lane];
        const float w3 = W_outT[(k + 3) * 64 + lane];
        const float4 x0 = *(const float4*)&h0[k];
        const float4 x1 = *(const float4*)&h1[k];
        a0 += w0 * x0.x + w1 * x0.y + w2 * x0.z + w3 * x0.w;
        a1 += w0 * x1.x + w1 * x1.y + w2 * x1.z + w3 * x1.w;
    }
    const float bo = b_out[lane];
    const float accs[2] = {a0, a1};

#pragma unroll
    for (int r = 0; r < 2; ++r) {
        const int row = r0 + r;
        const float lg = accs[r] + bo;

        float m = lg; int am = lane;
#pragma unroll
        for (int d = 1; d < 64; d <<= 1) {
            const float om = __shfl_xor(m, d);
            const int   oa = __shfl_xor(am, d);
            if (om > m || (om == m && oa < am)) { m = om; am = oa; }
        }
        float s = expf(lg - m);
#pragma unroll
        for (int d = 1; d < 64; d <<= 1) s += __shfl_xor(s, d);

        odig[(size_t)row * VOC + lane] = lg;
        omsg[(size_t)row * VOC + lane] = (lane == am) ? 1.0f : 0.0f;
        if (lane == 0) {
            const float prev = (t == 0) ? 0.0f : ologp[row];
            ologp[row] = prev - logf(s);   // log(probs[argmax]) = -log(sum exp(l-m))
        }

        // x_next = relu(emb[argmax]), pre-split: copy f16 rows
#pragma unroll
        for (int c = 0; c < 4; ++c) {
            const int off = c * 256 + lane * 4;
            *(f16x4*)&AhiN[(size_t)row * KA + off] = *(const f16x4*)&embHi[(size_t)am * HD + off];
            *(f16x4*)&AloN[(size_t)row * KA + off] = *(const f16x4*)&embLo[(size_t)am * HD + off];
        }
    }
}

// ---------------- prep kernels ----------------------------------------------
__global__ __launch_bounds__(256) void prep_w(
    const float* __restrict__ W_ih, const float* __restrict__ W_hh,
    f16* __restrict__ Whi, f16* __restrict__ Wlo)
{
    const long long idx = ((long long)blockIdx.x * 256 + threadIdx.x) * 4; // over NG*KA
    const int np = (int)(idx >> 11);
    const int k  = (int)(idx & 2047);
    const int bx = np >> 7, rem = np & 127;
    const int jh = rem >> 6, g = (rem >> 4) & 3, cnn = rem & 15;
    const int orig = g * 1024 + bx * 32 + jh * 16 + cnn;
    const float* src = (k < HD) ? &W_ih[(size_t)orig * HD + k]
                                : &W_hh[(size_t)orig * HD + (k - HD)];
    const float4 v = *(const float4*)src;
    f16x4 vh, vl; f16 hi_, lo_;
    splt(v.x, hi_, lo_); vh[0] = hi_; vl[0] = lo_;
    splt(v.y, hi_, lo_); vh[1] = hi_; vl[1] = lo_;
    splt(v.z, hi_, lo_); vh[2] = hi_; vl[2] = lo_;
    splt(v.w, hi_, lo_); vh[3] = hi_; vl[3] = lo_;
    *(f16x4*)&Whi[idx] = vh;
    *(f16x4*)&Wlo[idx] = vl;
}

__global__ __launch_bounds__(256) void prep_a(
    const float* __restrict__ ench, const float* __restrict__ x0,
    f16* __restrict__ Ahi, f16* __restrict__ Alo)
{
    const int idx = (blockIdx.x * 256 + threadIdx.x) * 4;   // over BATCH*KA
    const int b = idx >> 11;
    const int k = idx & 2047;
    float4 v;
    if (k < HD) {
        v = *(const float4*)&x0[k];   // broadcast row, relu applied
        v.x = fmaxf(v.x, 0.f); v.y = fmaxf(v.y, 0.f);
        v.z = fmaxf(v.z, 0.f); v.w = fmaxf(v.w, 0.f);
    } else {
        v = *(const float4*)&ench[(size_t)b * HD + (k - HD)];
    }
    f16x4 vh, vl; f16 hi_, lo_;
    splt(v.x, hi_, lo_); vh[0] = hi_; vl[0] = lo_;
    splt(v.y, hi_, lo_); vh[1] = hi_; vl[1] = lo_;
    splt(v.z, hi_, lo_); vh[2] = hi_; vl[2] = lo_;
    splt(v.w, hi_, lo_); vh[3] = hi_; vl[3] = lo_;
    *(f16x4*)&Ahi[idx] = vh;
    *(f16x4*)&Alo[idx] = vl;
}

__global__ __launch_bounds__(256) void prep_c(
    const float* __restrict__ encc, float* __restrict__ cbuf)
{
    const int idx = (blockIdx.x * 256 + threadIdx.x) * 4;
    *(float4*)&cbuf[idx] = *(const float4*)&encc[idx];
}

// one pass over 64K threads: mask, W_out transpose, emb relu+split, bias reorder
__global__ __launch_bounds__(256) void prep_small(
    const float* __restrict__ W_out, const float* __restrict__ b_ih,
    const float* __restrict__ b_hh, const float* __restrict__ emb,
    float* __restrict__ W_outT, f16* __restrict__ embHi, f16* __restrict__ embLo,
    float* __restrict__ bR, float* __restrict__ mask)
{
    const int i = blockIdx.x * 256 + threadIdx.x;   // 0..65535
    mask[i] = 1.0f;
    const int v = i >> 10, k = i & 1023;
    W_outT[k * 64 + v] = W_out[i];
    const float e = fmaxf(emb[i], 0.f);
    f16 hi_, lo_; splt(e, hi_, lo_);
    embHi[i] = hi_; embLo[i] = lo_;
    if (i < NG) {
        const int bx = i >> 7, rem = i & 127;
        const int jh = rem >> 6, g = (rem >> 4) & 3, cnn = rem & 15;
        const int orig = g * 1024 + bx * 32 + jh * 16 + cnn;
        bR[i] = b_ih[orig] + b_hh[orig];
    }
}

// ---------------- launch ----------------------------------------------------
extern "C" void kernel_launch(void* const* d_in, const int* in_sizes, int n_in,
                              void* d_out, int out_size, void* d_ws, size_t ws_size,
                              hipStream_t stream)
{
    const float* ench  = (const float*)d_in[0];
    const float* encc  = (const float*)d_in[1];
    const float* W_ih  = (const float*)d_in[2];
    const float* W_hh  = (const float*)d_in[3];
    const float* b_ih  = (const float*)d_in[4];
    const float* b_hh  = (const float*)d_in[5];
    const float* W_out = (const float*)d_in[6];
    const float* b_out = (const float*)d_in[7];
    const float* x0    = (const float*)d_in[8];
    const float* emb   = (const float*)d_in[9];
    float* out = (float*)d_out;

    char* ws = (char*)d_ws;
    f16*   Ah[2] = { (f16*)(ws + ((size_t) 0 << 20)), (f16*)(ws + ((size_t)32 << 20)) };
    f16*   Al[2] = { (f16*)(ws + ((size_t)16 << 20)), (f16*)(ws + ((size_t)48 << 20)) };
    f16*   Whi   = (f16*)(ws + ((size_t)64 << 20));
    f16*   Wlo   = (f16*)(ws + ((size_t)80 << 20));
    float* cbuf  = (float*)(ws + ((size_t) 96 << 20));
    float* hbuf  = (float*)(ws + ((size_t)112 << 20));
    float* W_outT= (float*)(ws + ((size_t)128 << 20));
    f16*   embHi = (f16*)(ws + ((size_t)129 << 20));
    f16*   embLo = (f16*)(ws + ((size_t)130 << 20));
    float* bR    = (float*)(ws + ((size_t)131 << 20));

    float* out_msg0 = out;                                        // [L,B,V]
    float* out_mask = out + (size_t)MSGL * BATCH * VOC;           // [L,1,B]
    float* out_dig0 = out_mask + (size_t)MSGL * BATCH;            // [L,B,V]
    float* out_logp = out_dig0 + (size_t)MSGL * BATCH * VOC;      // [B]

    prep_w<<<8192, 256, 0, stream>>>(W_ih, W_hh, Whi, Wlo);
    prep_a<<<8192, 256, 0, stream>>>(ench, x0, Ah[0], Al[0]);
    prep_c<<<4096, 256, 0, stream>>>(encc, cbuf);
    prep_small<<<256, 256, 0, stream>>>(W_out, b_ih, b_hh, emb,
                                        W_outT, embHi, embLo, bR, out_mask);

    for (int t = 0; t < MSGL; ++t) {
        const int cur = t & 1, nxt = cur ^ 1;
        gemm_fused<<<dim3(32, 32), 256, 0, stream>>>(
            Ah[cur], Al[cur], Whi, Wlo, bR, cbuf, hbuf, Ah[nxt], Al[nxt]);
        logits_step<<<512, 256, 0, stream>>>(
            hbuf, W_outT, b_out, embHi, embLo, Ah[nxt], Al[nxt],
            out_msg0 + (size_t)t * BATCH * VOC,
            out_dig0 + (size_t)t * BATCH * VOC,
            out_logp, t);
    }
}

// Round 3
// 2745.123 us; speedup vs baseline: 1.9821x; 1.4532x over previous
//
#include <hip/hip_runtime.h>
#include <math.h>

#define HD    1024
#define BATCH 4096
#define VOC   64
#define MSGL  16
#define KH    1024   // GEMM K = hidden only (x-half folded into XG table)
#define NG    4096   // gates width = 4H

typedef _Float16 f16;
typedef _Float16 f16x8 __attribute__((ext_vector_type(8)));
typedef _Float16 f16x4 __attribute__((ext_vector_type(4)));
typedef float    f32x4 __attribute__((ext_vector_type(4)));

__device__ __forceinline__ void splt(float v, f16& hi, f16& lo) {
    f16 h = (f16)v;
    hi = h;
    lo = (f16)(v - (float)h);
}

__device__ __forceinline__ float sigm(float x) { return 1.0f / (1.0f + expf(-x)); }

// permuted gate index: n' = bx*128 + jh*64 + g*16 + cn  ->  orig n = g*1024 + j
__device__ __forceinline__ int orig_n(int np) {
    const int bx = np >> 7, rem = np & 127;
    const int jh = rem >> 6, g = (rem >> 4) & 3, cnn = rem & 15;
    return g * 1024 + bx * 32 + jh * 16 + cnn;
}

__device__ __forceinline__ void async16(void* lds, const void* g) {
    __builtin_amdgcn_global_load_lds(
        (const __attribute__((address_space(1))) void*)g,
        (__attribute__((address_space(3))) void*)lds, 16, 0, 0);
}

// ---------------- fused gates GEMM (K=1024) + XG gather + LSTM cell ---------
// acc = h @ W_hh_perm^T  (fp16 hi/lo split, 3-pass MFMA, fp32 accumulate)
// gates = acc + XG[v][n']   where v = argmax of prev step (64 = t0 row, bias folded)
// 128x128 tile, 4 waves (2x2). Epilogue LDS-staged for coalesced c/h I/O.
__global__ __launch_bounds__(256) void gemm_fused(
    const f16* __restrict__ Ahi, const f16* __restrict__ Alo,
    const f16* __restrict__ Whi, const f16* __restrict__ Wlo,
    const float* __restrict__ XG, const int* __restrict__ ambuf,
    float* __restrict__ cbuf,
    f16* __restrict__ HhN, f16* __restrict__ HlN, int t)
{
    __shared__ f16 sT[4][128 * 32];   // 32 KB: K-loop tiles; epilogue overlay
    __shared__ int sAm[128];
    f16* sAh = sT[0]; f16* sAl = sT[1]; f16* sBh = sT[2]; f16* sBl = sT[3];

    const int tid  = threadIdx.x;
    const int lane = tid & 63;
    const int wv   = tid >> 6;
    const int wm   = wv >> 1;
    const int wn   = wv & 1;
    const int bm   = blockIdx.y * 128;      // batch rows
    const int bnp  = blockIdx.x * 128;      // permuted gate cols

    const int srow = tid >> 2;
    const int scol = (tid & 3) * 8;

    f32x4 zero = {0.f, 0.f, 0.f, 0.f};
    f32x4 acc[4][4];
#pragma unroll
    for (int i = 0; i < 4; ++i)
#pragma unroll
        for (int j = 0; j < 4; ++j) acc[i][j] = zero;

    for (int k0 = 0; k0 < KH; k0 += 32) {
        __syncthreads();
#pragma unroll
        for (int r = 0; r < 2; ++r) {
            const int row = srow + r * 64;
            const size_t ga = (size_t)(bm + row) * KH + k0 + scol;
            const size_t gb = (size_t)(bnp + row) * KH + k0 + scol;
            const int lo = row * 32 + scol;
            async16(&sAh[lo], Ahi + ga);
            async16(&sAl[lo], Alo + ga);
            async16(&sBh[lo], Whi + gb);
            async16(&sBl[lo], Wlo + gb);
        }
        __syncthreads();

        f16x8 fah[4], fal[4], fbh[4], fbl[4];
        const int ks = (lane >> 4) * 8;
#pragma unroll
        for (int i = 0; i < 4; ++i) {
            const int ar = wm * 64 + i * 16 + (lane & 15);
            fah[i] = *(const f16x8*)&sAh[ar * 32 + ks];
            fal[i] = *(const f16x8*)&sAl[ar * 32 + ks];
            const int br = wn * 64 + i * 16 + (lane & 15);
            fbh[i] = *(const f16x8*)&sBh[br * 32 + ks];
            fbl[i] = *(const f16x8*)&sBl[br * 32 + ks];
        }
#pragma unroll
        for (int i = 0; i < 4; ++i)
#pragma unroll
            for (int j = 0; j < 4; ++j) {
                acc[i][j] = __builtin_amdgcn_mfma_f32_16x16x32_f16(fah[i], fbh[j], acc[i][j], 0, 0, 0);
                acc[i][j] = __builtin_amdgcn_mfma_f32_16x16x32_f16(fah[i], fbl[j], acc[i][j], 0, 0, 0);
                acc[i][j] = __builtin_amdgcn_mfma_f32_16x16x32_f16(fal[i], fbh[j], acc[i][j], 0, 0, 0);
            }
    }

    // ---- epilogue ----
    __syncthreads();                              // done with K-loop LDS
    float* cS  = (float*)&sT[0][0];               // [128][32] f32 (16 KB)
    f16*   hHi = (f16*)((char*)&sT[0][0] + 16384);// [128][32]
    f16*   hLo = (f16*)((char*)&sT[0][0] + 24576);// [128][32]

    {   // coalesced stage-in of cbuf tile + argmax ids
        const int r  = tid >> 3;
        const int c4 = (tid & 7) * 4;
#pragma unroll
        for (int p = 0; p < 4; ++p) {
            const int row = p * 32 + r;
            *(float4*)&cS[row * 32 + c4] =
                *(const float4*)&cbuf[(size_t)(bm + row) * HD + blockIdx.x * 32 + c4];
        }
        if (tid < 128) sAm[tid] = (t == 0) ? 64 : ambuf[bm + tid];
    }
    __syncthreads();

    const int q  = lane >> 4;
    const int cn = lane & 15;
    const int lcol = wn * 16 + cn;
#pragma unroll
    for (int i = 0; i < 4; ++i) {
#pragma unroll
        for (int rg = 0; rg < 4; ++rg) {
            const int lrow = wm * 64 + i * 16 + q * 4 + rg;
            const int v = sAm[lrow];
            const float* xg = &XG[(size_t)v * NG + bnp + wn * 64 + cn];
            const float iv = acc[i][0][rg] + xg[0];
            const float fv = acc[i][1][rg] + xg[16];
            const float gv = acc[i][2][rg] + xg[32];
            const float ov = acc[i][3][rg] + xg[48];
            const float cold = cS[lrow * 32 + lcol];
            const float I = sigm(iv);
            const float F = sigm(fv);
            const float G = tanhf(gv);
            const float O = sigm(ov);
            const float cc = F * cold + I * G;
            const float hh = O * tanhf(cc);
            cS[lrow * 32 + lcol] = cc;
            f16 hi_, lo_;
            splt(hh, hi_, lo_);
            hHi[lrow * 32 + lcol] = hi_;
            hLo[lrow * 32 + lcol] = lo_;
        }
    }
    __syncthreads();

    {   // coalesced write-out: cbuf, next-step h (hi/lo)
        const int r  = tid >> 3;
        const int c4 = (tid & 7) * 4;
#pragma unroll
        for (int p = 0; p < 4; ++p) {
            const int row = p * 32 + r;
            *(float4*)&cbuf[(size_t)(bm + row) * HD + blockIdx.x * 32 + c4] =
                *(float4*)&cS[row * 32 + c4];
            *(f16x4*)&HhN[(size_t)(bm + row) * HD + blockIdx.x * 32 + c4] =
                *(f16x4*)&hHi[row * 32 + c4];
            *(f16x4*)&HlN[(size_t)(bm + row) * HD + blockIdx.x * 32 + c4] =
                *(f16x4*)&hLo[row * 32 + c4];
        }
    }
}

// ---------------- logits + softmax + argmax + outputs -----------------------
// 4 waves/block, 2 rows per wave; lane == vocab index (V=64)
__global__ __launch_bounds__(256) void logits_step(
    const f16* __restrict__ Hh, const f16* __restrict__ Hl,
    const float* __restrict__ W_outT, const float* __restrict__ b_out,
    float* __restrict__ omsg, float* __restrict__ odig,
    float* __restrict__ ologp, int* __restrict__ ambuf, int t)
{
    const int lane = threadIdx.x & 63;
    const int wv   = threadIdx.x >> 6;
    const int r0   = blockIdx.x * 8 + wv * 2;

    float a0 = 0.f, a1 = 0.f;
    const f16* hh0 = Hh + (size_t)r0 * HD;
    const f16* hl0 = Hl + (size_t)r0 * HD;
    const f16* hh1 = hh0 + HD;
    const f16* hl1 = hl0 + HD;
    for (int k = 0; k < HD; k += 4) {
        const float w0 = W_outT[(k + 0) * 64 + lane];
        const float w1 = W_outT[(k + 1) * 64 + lane];
        const float w2 = W_outT[(k + 2) * 64 + lane];
        const float w3 = W_outT[(k + 3) * 64 + lane];
        const f16x4 vh0 = *(const f16x4*)&hh0[k];
        const f16x4 vl0 = *(const f16x4*)&hl0[k];
        const f16x4 vh1 = *(const f16x4*)&hh1[k];
        const f16x4 vl1 = *(const f16x4*)&hl1[k];
        a0 += w0 * ((float)vh0[0] + (float)vl0[0]) + w1 * ((float)vh0[1] + (float)vl0[1])
            + w2 * ((float)vh0[2] + (float)vl0[2]) + w3 * ((float)vh0[3] + (float)vl0[3]);
        a1 += w0 * ((float)vh1[0] + (float)vl1[0]) + w1 * ((float)vh1[1] + (float)vl1[1])
            + w2 * ((float)vh1[2] + (float)vl1[2]) + w3 * ((float)vh1[3] + (float)vl1[3]);
    }
    const float bo = b_out[lane];
    const float accs[2] = {a0, a1};

#pragma unroll
    for (int r = 0; r < 2; ++r) {
        const int row = r0 + r;
        const float lg = accs[r] + bo;

        float m = lg; int am = lane;
#pragma unroll
        for (int d = 1; d < 64; d <<= 1) {
            const float om = __shfl_xor(m, d);
            const int   oa = __shfl_xor(am, d);
            if (om > m || (om == m && oa < am)) { m = om; am = oa; }
        }
        float s = expf(lg - m);
#pragma unroll
        for (int d = 1; d < 64; d <<= 1) s += __shfl_xor(s, d);

        odig[(size_t)row * VOC + lane] = lg;
        omsg[(size_t)row * VOC + lane] = (lane == am) ? 1.0f : 0.0f;
        if (lane == 0) {
            const float prev = (t == 0) ? 0.0f : ologp[row];
            ologp[row] = prev - logf(s);   // log(probs[argmax]) = -log(sum exp(l-m))
            ambuf[row] = am;
        }
    }
}

// ---------------- XG table: XG[v][n'] = relu(x_v) @ W_ih^T + b_ih + b_hh ----
// one wave per n'; lane == v (0..63); lane 0 also writes the t=0 row (v=64).
__global__ __launch_bounds__(256) void xg_kernel(
    const float* __restrict__ W_ih, const float* __restrict__ rembT,  // [1024][64]
    const float* __restrict__ rembX0, const float* __restrict__ bR,
    float* __restrict__ XG)                                           // [65][4096]
{
    __shared__ float sW[4][1024];
    const int lane = threadIdx.x & 63;
    const int wv   = threadIdx.x >> 6;
    const int np   = blockIdx.x * 4 + wv;
    const int orig = orig_n(np);
    const float* wr = W_ih + (size_t)orig * HD;
#pragma unroll
    for (int c = 0; c < 4; ++c)
        *(float4*)&sW[wv][c * 256 + lane * 4] = *(const float4*)&wr[c * 256 + lane * 4];
    __syncthreads();

    float acc = 0.f, acc0 = 0.f;
#pragma unroll 4
    for (int k = 0; k < HD; ++k) {
        const float w = sW[wv][k];
        acc  += w * rembT[k * 64 + lane];
        acc0 += w * rembX0[k];
    }
    const float b = bR[np];
    XG[(size_t)lane * NG + np] = acc + b;
    if (lane == 0) XG[(size_t)64 * NG + np] = acc0 + b;
}

// ---------------- prep kernels ----------------------------------------------
__global__ __launch_bounds__(256) void prep_w(
    const float* __restrict__ W_hh, f16* __restrict__ Whi, f16* __restrict__ Wlo)
{
    const long long idx = ((long long)blockIdx.x * 256 + threadIdx.x) * 4; // NG*KH
    const int np = (int)(idx >> 10);
    const int k  = (int)(idx & 1023);
    const float4 v = *(const float4*)&W_hh[(size_t)orig_n(np) * HD + k];
    f16x4 vh, vl; f16 hi_, lo_;
    splt(v.x, hi_, lo_); vh[0] = hi_; vl[0] = lo_;
    splt(v.y, hi_, lo_); vh[1] = hi_; vl[1] = lo_;
    splt(v.z, hi_, lo_); vh[2] = hi_; vl[2] = lo_;
    splt(v.w, hi_, lo_); vh[3] = hi_; vl[3] = lo_;
    *(f16x4*)&Whi[idx] = vh;
    *(f16x4*)&Wlo[idx] = vl;
}

__global__ __launch_bounds__(256) void prep_h(
    const float* __restrict__ ench, f16* __restrict__ Hh, f16* __restrict__ Hl)
{
    const int idx = (blockIdx.x * 256 + threadIdx.x) * 4;   // BATCH*HD
    const float4 v = *(const float4*)&ench[idx];
    f16x4 vh, vl; f16 hi_, lo_;
    splt(v.x, hi_, lo_); vh[0] = hi_; vl[0] = lo_;
    splt(v.y, hi_, lo_); vh[1] = hi_; vl[1] = lo_;
    splt(v.z, hi_, lo_); vh[2] = hi_; vl[2] = lo_;
    splt(v.w, hi_, lo_); vh[3] = hi_; vl[3] = lo_;
    *(f16x4*)&Hh[idx] = vh;
    *(f16x4*)&Hl[idx] = vl;
}

__global__ __launch_bounds__(256) void prep_c(
    const float* __restrict__ encc, float* __restrict__ cbuf)
{
    const int idx = (blockIdx.x * 256 + threadIdx.x) * 4;
    *(float4*)&cbuf[idx] = *(const float4*)&encc[idx];
}

// mask, W_out transpose, relu(emb) transpose, relu(x0), bias reorder
__global__ __launch_bounds__(256) void prep_small(
    const float* __restrict__ W_out, const float* __restrict__ b_ih,
    const float* __restrict__ b_hh, const float* __restrict__ emb,
    const float* __restrict__ x0,
    float* __restrict__ W_outT, float* __restrict__ rembT,
    float* __restrict__ rembX0, float* __restrict__ bR, float* __restrict__ mask)
{
    const int i = blockIdx.x * 256 + threadIdx.x;   // 0..65535
    mask[i] = 1.0f;
    const int v = i >> 10, k = i & 1023;
    W_outT[k * 64 + v] = W_out[i];
    rembT[k * 64 + v] = fmaxf(emb[i], 0.f);
    if (i < 1024) rembX0[i] = fmaxf(x0[i], 0.f);
    if (i < NG) {
        const int orig = orig_n(i);
        bR[i] = b_ih[orig] + b_hh[orig];
    }
}

// ---------------- launch ----------------------------------------------------
extern "C" void kernel_launch(void* const* d_in, const int* in_sizes, int n_in,
                              void* d_out, int out_size, void* d_ws, size_t ws_size,
                              hipStream_t stream)
{
    const float* ench  = (const float*)d_in[0];
    const float* encc  = (const float*)d_in[1];
    const float* W_ih  = (const float*)d_in[2];
    const float* W_hh  = (const float*)d_in[3];
    const float* b_ih  = (const float*)d_in[4];
    const float* b_hh  = (const float*)d_in[5];
    const float* W_out = (const float*)d_in[6];
    const float* b_out = (const float*)d_in[7];
    const float* x0    = (const float*)d_in[8];
    const float* emb   = (const float*)d_in[9];
    float* out = (float*)d_out;

    char* ws = (char*)d_ws;
    f16*   Hh[2]  = { (f16*)(ws + ((size_t) 0 << 20)), (f16*)(ws + ((size_t)16 << 20)) };
    f16*   Hl[2]  = { (f16*)(ws + ((size_t) 8 << 20)), (f16*)(ws + ((size_t)24 << 20)) };
    f16*   Whr    = (f16*)(ws + ((size_t)32 << 20));
    f16*   Wlr    = (f16*)(ws + ((size_t)40 << 20));
    float* cbuf   = (float*)(ws + ((size_t)48 << 20));
    float* W_outT = (float*)(ws + ((size_t)64 << 20));
    float* rembT  = (float*)(ws + ((size_t)65 << 20));
    float* rembX0 = (float*)(ws + ((size_t)66 << 20));
    float* bR     = (float*)(ws + ((size_t)66 << 20) + 8192);
    float* XG     = (float*)(ws + ((size_t)67 << 20));
    int*   ambuf  = (int*)  (ws + ((size_t)69 << 20));

    float* out_msg0 = out;                                        // [L,B,V]
    float* out_mask = out + (size_t)MSGL * BATCH * VOC;           // [L,1,B]
    float* out_dig0 = out_mask + (size_t)MSGL * BATCH;            // [L,B,V]
    float* out_logp = out_dig0 + (size_t)MSGL * BATCH * VOC;      // [B]

    prep_w<<<4096, 256, 0, stream>>>(W_hh, Whr, Wlr);
    prep_h<<<4096, 256, 0, stream>>>(ench, Hh[0], Hl[0]);
    prep_c<<<4096, 256, 0, stream>>>(encc, cbuf);
    prep_small<<<256, 256, 0, stream>>>(W_out, b_ih, b_hh, emb, x0,
                                        W_outT, rembT, rembX0, bR, out_mask);
    xg_kernel<<<1024, 256, 0, stream>>>(W_ih, rembT, rembX0, bR, XG);

    for (int t = 0; t < MSGL; ++t) {
        const int cur = t & 1, nxt = cur ^ 1;
        gemm_fused<<<dim3(32, 32), 256, 0, stream>>>(
            Hh[cur], Hl[cur], Whr, Wlr, XG, ambuf, cbuf, Hh[nxt], Hl[nxt], t);
        logits_step<<<512, 256, 0, stream>>>(
            Hh[nxt], Hl[nxt], W_outT, b_out,
            out_msg0 + (size_t)t * BATCH * VOC,
            out_dig0 + (size_t)t * BATCH * VOC,
            out_logp, ambuf, t);
    }
}

// Round 4
// 2554.663 us; speedup vs baseline: 2.1299x; 1.0746x over previous
//
#include <hip/hip_runtime.h>
#include <math.h>

#define HD    1024
#define BATCH 4096
#define VOC   64
#define MSGL  16
#define KH    1024   // GEMM K = hidden only (x-half folded into XG table)
#define NG    4096   // gates width = 4H

typedef _Float16 f16;
typedef _Float16 f16x8 __attribute__((ext_vector_type(8)));
typedef _Float16 f16x4 __attribute__((ext_vector_type(4)));
typedef float    f32x4 __attribute__((ext_vector_type(4)));

__device__ __forceinline__ void splt(float v, f16& hi, f16& lo) {
    f16 h = (f16)v;
    hi = h;
    lo = (f16)(v - (float)h);
}

__device__ __forceinline__ float sigm(float x) { return 1.0f / (1.0f + expf(-x)); }

// permuted gate index for 256-wide tiles:
//   n' = bxx*256 + jh*64 + g*16 + cn   (bxx=n'>>8, jh in 0..3, g in 0..3)
//   j  = bxx*64 + jh*16 + cn,  orig n = g*1024 + j
__device__ __forceinline__ int orig_n(int np) {
    const int bxx = np >> 8, rem = np & 255;
    const int jh = rem >> 6, g = (rem >> 4) & 3, cnn = rem & 15;
    return g * 1024 + bxx * 64 + jh * 16 + cnn;
}
__device__ __forceinline__ int j_of(int np) {
    const int bxx = np >> 8, rem = np & 255;
    const int jh = rem >> 6, cnn = rem & 15;
    return bxx * 64 + jh * 16 + cnn;
}

__device__ __forceinline__ void async16(void* lds, const void* g) {
    __builtin_amdgcn_global_load_lds(
        (const __attribute__((address_space(1))) void*)g,
        (__attribute__((address_space(3))) void*)lds, 16, 0, 0);
}

// swizzled byte offset in a [256-row][128B-row] LDS tile; granule = 16B unit 0..7
__device__ __forceinline__ int swz(int row, int gran) {
    return row * 128 + ((gran ^ (row & 7)) << 4);
}

// stage one 8KB round of a [256][128B] tile: linear LDS dest (gload_lds
// requirement), inverse-swizzled global source (rule: both-sides-or-neither).
// granules 0..3 = hi k-slices, 4..7 = lo k-slices.
__device__ __forceinline__ void stage(char* ldsbase, const f16* hi, const f16* lo,
                                      int gbase, int k0, int r, int tid) {
    const int o   = (r * 512 + tid) * 16;   // byte offset in 32KB tile
    const int row = o >> 7;
    const int gp  = (o >> 4) & 7;
    const int g   = gp ^ (row & 7);
    const f16* src = (g < 4 ? hi : lo) + (size_t)(gbase + row) * KH + k0 + (g & 3) * 8;
    async16(ldsbase + o, src);
}

// ---------------- fused gates GEMM (K=1024) + XG gather + LSTM cell ---------
// 256x256 tile, 8 waves (2Mx4N), per-wave 128x64. fp16 hi/lo 3-pass MFMA.
// Phase-interleaved K-loop: 4 phases/K-tile, staging in flight across
// barriers, vmcnt(0) once per K-tile at tile top (= counted wait at depth-1).
__global__ __launch_bounds__(512, 2) void gemm_fused(
    const f16* __restrict__ Hh, const f16* __restrict__ Hl,
    const f16* __restrict__ Whi, const f16* __restrict__ Wlo,
    const float* __restrict__ XG, const int* __restrict__ ambuf,
    float* __restrict__ cbuf,
    f16* __restrict__ HhN, f16* __restrict__ HlN, int t)
{
    __shared__ char smem[131072];           // [A dbuf 64K][B dbuf 64K]
    __shared__ int sAm[256];

    const int tid  = threadIdx.x;
    const int lane = tid & 63;
    const int wv   = tid >> 6;              // 0..7
    const int wm   = wv >> 2;               // 0..1 (M half)
    const int wn   = wv & 3;                // 0..3 (N quarter)
    const int bm   = blockIdx.y * 256;      // batch rows
    const int bnp  = blockIdx.x * 256;      // permuted gate cols
    const int rl   = lane & 15;
    const int kg   = lane >> 4;             // k-granule 0..3

    char* sA = smem;                        // A: 2 x 32KB
    char* sB = smem + 65536;                // B: 2 x 32KB

    f32x4 acc[8][4];
#pragma unroll
    for (int i = 0; i < 8; ++i)
#pragma unroll
        for (int g = 0; g < 4; ++g) acc[i][g] = f32x4{0.f, 0.f, 0.f, 0.f};

    // prologue: stage K-tile 0; argmax ids
#pragma unroll
    for (int r = 0; r < 4; ++r) {
        stage(sA, Hh, Hl, bm, 0, r, tid);
        stage(sB, Whi, Wlo, bnp, 0, r, tid);
    }
    if (tid < 256) sAm[tid] = (t == 0) ? 64 : ambuf[bm + tid];

    for (int kt = 0; kt < 32; ++kt) {
        const char* pA = sA + (kt & 1) * 32768;
        const char* pB = sB + (kt & 1) * 32768;
        char* nA = sA + ((kt + 1) & 1) * 32768;
        char* nB = sB + ((kt + 1) & 1) * 32768;
        const int kn = (kt + 1) * 32;

        asm volatile("s_waitcnt vmcnt(0)" ::: "memory");
        __builtin_amdgcn_sched_barrier(0);
        __builtin_amdgcn_s_barrier();

        f16x8 bh[4], bl[4];
#pragma unroll
        for (int p = 0; p < 4; ++p) {
            f16x8 ah[2], al[2];
#pragma unroll
            for (int ii = 0; ii < 2; ++ii) {
                const int ar = wm * 128 + (p * 2 + ii) * 16 + rl;
                ah[ii] = *(const f16x8*)(pA + swz(ar, kg));
                al[ii] = *(const f16x8*)(pA + swz(ar, kg + 4));
            }
            if (p == 0) {
#pragma unroll
                for (int g = 0; g < 4; ++g) {
                    const int br = wn * 64 + g * 16 + rl;
                    bh[g] = *(const f16x8*)(pB + swz(br, kg));
                    bl[g] = *(const f16x8*)(pB + swz(br, kg + 4));
                }
                if (kt < 31) {
#pragma unroll
                    for (int r = 0; r < 4; ++r) stage(nA, Hh, Hl, bm, kn, r, tid);
                }
            }
            if (p == 1 && kt < 31) {
#pragma unroll
                for (int r = 0; r < 4; ++r) stage(nB, Whi, Wlo, bnp, kn, r, tid);
            }
            __builtin_amdgcn_s_barrier();
            __builtin_amdgcn_s_setprio(1);
#pragma unroll
            for (int ii = 0; ii < 2; ++ii) {
                const int i = p * 2 + ii;
#pragma unroll
                for (int g = 0; g < 4; ++g) {
                    acc[i][g] = __builtin_amdgcn_mfma_f32_16x16x32_f16(ah[ii], bh[g], acc[i][g], 0, 0, 0);
                    acc[i][g] = __builtin_amdgcn_mfma_f32_16x16x32_f16(ah[ii], bl[g], acc[i][g], 0, 0, 0);
                    acc[i][g] = __builtin_amdgcn_mfma_f32_16x16x32_f16(al[ii], bh[g], acc[i][g], 0, 0, 0);
                }
            }
            __builtin_amdgcn_s_setprio(0);
            __builtin_amdgcn_s_barrier();
        }
    }

    // ---- epilogue: LSTM cell, LDS-staged for coalesced c/h I/O ----
    __syncthreads();
    float* cS  = (float*)smem;              // [256][64] f32 (64 KB)
    f16*   hHi = (f16*)(smem + 65536);      // [256][64] (32 KB)
    f16*   hLo = (f16*)(smem + 98304);      // [256][64] (32 KB)
    const int jb = blockIdx.x * 64;         // j column base

#pragma unroll
    for (int r = 0; r < 8; ++r) {
        const int idx = r * 512 + tid;      // 0..4095
        const int row = idx >> 4;
        const int c4  = (idx & 15) * 4;
        *(float4*)&cS[row * 64 + c4] =
            *(const float4*)&cbuf[(size_t)(bm + row) * HD + jb + c4];
    }
    __syncthreads();

    const int q    = lane >> 4;
    const int lcol = wn * 16 + rl;
    const int jglob = jb + lcol;
#pragma unroll
    for (int i = 0; i < 8; ++i) {
#pragma unroll
        for (int rg = 0; rg < 4; ++rg) {
            const int lrow = wm * 128 + i * 16 + q * 4 + rg;
            const int v = sAm[lrow];
            const float4 xg = *(const float4*)&XG[(size_t)v * NG + jglob * 4];
            const float iv = acc[i][0][rg] + xg.x;
            const float fv = acc[i][1][rg] + xg.y;
            const float gv = acc[i][2][rg] + xg.z;
            const float ov = acc[i][3][rg] + xg.w;
            const float cold = cS[lrow * 64 + lcol];
            const float I = sigm(iv);
            const float F = sigm(fv);
            const float G = tanhf(gv);
            const float O = sigm(ov);
            const float cc = F * cold + I * G;
            const float hh = O * tanhf(cc);
            cS[lrow * 64 + lcol] = cc;
            f16 hi_, lo_;
            splt(hh, hi_, lo_);
            hHi[lrow * 64 + lcol] = hi_;
            hLo[lrow * 64 + lcol] = lo_;
        }
    }
    __syncthreads();

#pragma unroll
    for (int r = 0; r < 8; ++r) {
        const int idx = r * 512 + tid;
        const int row = idx >> 4;
        const int c4  = (idx & 15) * 4;
        *(float4*)&cbuf[(size_t)(bm + row) * HD + jb + c4] = *(float4*)&cS[row * 64 + c4];
        *(f16x4*)&HhN[(size_t)(bm + row) * HD + jb + c4]   = *(f16x4*)&hHi[row * 64 + c4];
        *(f16x4*)&HlN[(size_t)(bm + row) * HD + jb + c4]   = *(f16x4*)&hLo[row * 64 + c4];
    }
}

// ---------------- logits + softmax + argmax + outputs -----------------------
// 4 waves/block, 2 rows per wave; lane == vocab index (V=64)
__global__ __launch_bounds__(256) void logits_step(
    const f16* __restrict__ Hh, const f16* __restrict__ Hl,
    const float* __restrict__ W_outT, const float* __restrict__ b_out,
    float* __restrict__ omsg, float* __restrict__ odig,
    float* __restrict__ ologp, int* __restrict__ ambuf, int t)
{
    const int lane = threadIdx.x & 63;
    const int wv   = threadIdx.x >> 6;
    const int r0   = blockIdx.x * 8 + wv * 2;

    float a0 = 0.f, a1 = 0.f;
    const f16* hh0 = Hh + (size_t)r0 * HD;
    const f16* hl0 = Hl + (size_t)r0 * HD;
    const f16* hh1 = hh0 + HD;
    const f16* hl1 = hl0 + HD;
    for (int k = 0; k < HD; k += 4) {
        const float w0 = W_outT[(k + 0) * 64 + lane];
        const float w1 = W_outT[(k + 1) * 64 + lane];
        const float w2 = W_outT[(k + 2) * 64 + lane];
        const float w3 = W_outT[(k + 3) * 64 + lane];
        const f16x4 vh0 = *(const f16x4*)&hh0[k];
        const f16x4 vl0 = *(const f16x4*)&hl0[k];
        const f16x4 vh1 = *(const f16x4*)&hh1[k];
        const f16x4 vl1 = *(const f16x4*)&hl1[k];
        a0 += w0 * ((float)vh0[0] + (float)vl0[0]) + w1 * ((float)vh0[1] + (float)vl0[1])
            + w2 * ((float)vh0[2] + (float)vl0[2]) + w3 * ((float)vh0[3] + (float)vl0[3]);
        a1 += w0 * ((float)vh1[0] + (float)vl1[0]) + w1 * ((float)vh1[1] + (float)vl1[1])
            + w2 * ((float)vh1[2] + (float)vl1[2]) + w3 * ((float)vh1[3] + (float)vl1[3]);
    }
    const float bo = b_out[lane];
    const float accs[2] = {a0, a1};

#pragma unroll
    for (int r = 0; r < 2; ++r) {
        const int row = r0 + r;
        const float lg = accs[r] + bo;

        float m = lg; int am = lane;
#pragma unroll
        for (int d = 1; d < 64; d <<= 1) {
            const float om = __shfl_xor(m, d);
            const int   oa = __shfl_xor(am, d);
            if (om > m || (om == m && oa < am)) { m = om; am = oa; }
        }
        float s = expf(lg - m);
#pragma unroll
        for (int d = 1; d < 64; d <<= 1) s += __shfl_xor(s, d);

        odig[(size_t)row * VOC + lane] = lg;
        omsg[(size_t)row * VOC + lane] = (lane == am) ? 1.0f : 0.0f;
        if (lane == 0) {
            const float prev = (t == 0) ? 0.0f : ologp[row];
            ologp[row] = prev - logf(s);   // log(probs[argmax]) = -log(sum exp(l-m))
            ambuf[row] = am;
        }
    }
}

// ---------------- XG table: XG[v][j*4+g] = relu(x_v)@W_ih^T + b_ih + b_hh ---
// one wave per n'; lane == v (0..63); lane 0 also writes the t=0 row (v=64).
__global__ __launch_bounds__(256) void xg_kernel(
    const float* __restrict__ W_ih, const float* __restrict__ rembT,  // [1024][64]
    const float* __restrict__ rembX0, const float* __restrict__ bR,
    float* __restrict__ XG)                                           // [65][4096]
{
    __shared__ float sW[4][1024];
    const int lane = threadIdx.x & 63;
    const int wv   = threadIdx.x >> 6;
    const int np   = blockIdx.x * 4 + wv;
    const int orig = orig_n(np);
    const float* wr = W_ih + (size_t)orig * HD;
#pragma unroll
    for (int c = 0; c < 4; ++c)
        *(float4*)&sW[wv][c * 256 + lane * 4] = *(const float4*)&wr[c * 256 + lane * 4];
    __syncthreads();

    float acc = 0.f, acc0 = 0.f;
#pragma unroll 4
    for (int k = 0; k < HD; ++k) {
        const float w = sW[wv][k];
        acc  += w * rembT[k * 64 + lane];
        acc0 += w * rembX0[k];
    }
    const float b = bR[np];
    const int g = (np >> 4) & 3;
    const int pos = j_of(np) * 4 + g;
    XG[(size_t)lane * NG + pos] = acc + b;
    if (lane == 0) XG[(size_t)64 * NG + pos] = acc0 + b;
}

// ---------------- prep kernels ----------------------------------------------
__global__ __launch_bounds__(256) void prep_w(
    const float* __restrict__ W_hh, f16* __restrict__ Whi, f16* __restrict__ Wlo)
{
    const long long idx = ((long long)blockIdx.x * 256 + threadIdx.x) * 4; // NG*KH
    const int np = (int)(idx >> 10);
    const int k  = (int)(idx & 1023);
    const float4 v = *(const float4*)&W_hh[(size_t)orig_n(np) * HD + k];
    f16x4 vh, vl; f16 hi_, lo_;
    splt(v.x, hi_, lo_); vh[0] = hi_; vl[0] = lo_;
    splt(v.y, hi_, lo_); vh[1] = hi_; vl[1] = lo_;
    splt(v.z, hi_, lo_); vh[2] = hi_; vl[2] = lo_;
    splt(v.w, hi_, lo_); vh[3] = hi_; vl[3] = lo_;
    *(f16x4*)&Whi[idx] = vh;
    *(f16x4*)&Wlo[idx] = vl;
}

__global__ __launch_bounds__(256) void prep_h(
    const float* __restrict__ ench, f16* __restrict__ Hh, f16* __restrict__ Hl)
{
    const int idx = (blockIdx.x * 256 + threadIdx.x) * 4;   // BATCH*HD
    const float4 v = *(const float4*)&ench[idx];
    f16x4 vh, vl; f16 hi_, lo_;
    splt(v.x, hi_, lo_); vh[0] = hi_; vl[0] = lo_;
    splt(v.y, hi_, lo_); vh[1] = hi_; vl[1] = lo_;
    splt(v.z, hi_, lo_); vh[2] = hi_; vl[2] = lo_;
    splt(v.w, hi_, lo_); vh[3] = hi_; vl[3] = lo_;
    *(f16x4*)&Hh[idx] = vh;
    *(f16x4*)&Hl[idx] = vl;
}

__global__ __launch_bounds__(256) void prep_c(
    const float* __restrict__ encc, float* __restrict__ cbuf)
{
    const int idx = (blockIdx.x * 256 + threadIdx.x) * 4;
    *(float4*)&cbuf[idx] = *(const float4*)&encc[idx];
}

// mask, W_out transpose, relu(emb) transpose, relu(x0), bias reorder
__global__ __launch_bounds__(256) void prep_small(
    const float* __restrict__ W_out, const float* __restrict__ b_ih,
    const float* __restrict__ b_hh, const float* __restrict__ emb,
    const float* __restrict__ x0,
    float* __restrict__ W_outT, float* __restrict__ rembT,
    float* __restrict__ rembX0, float* __restrict__ bR, float* __restrict__ mask)
{
    const int i = blockIdx.x * 256 + threadIdx.x;   // 0..65535
    mask[i] = 1.0f;
    const int v = i >> 10, k = i & 1023;
    W_outT[k * 64 + v] = W_out[i];
    rembT[k * 64 + v] = fmaxf(emb[i], 0.f);
    if (i < 1024) rembX0[i] = fmaxf(x0[i], 0.f);
    if (i < NG) {
        const int orig = orig_n(i);
        bR[i] = b_ih[orig] + b_hh[orig];
    }
}

// ---------------- launch ----------------------------------------------------
extern "C" void kernel_launch(void* const* d_in, const int* in_sizes, int n_in,
                              void* d_out, int out_size, void* d_ws, size_t ws_size,
                              hipStream_t stream)
{
    const float* ench  = (const float*)d_in[0];
    const float* encc  = (const float*)d_in[1];
    const float* W_ih  = (const float*)d_in[2];
    const float* W_hh  = (const float*)d_in[3];
    const float* b_ih  = (const float*)d_in[4];
    const float* b_hh  = (const float*)d_in[5];
    const float* W_out = (const float*)d_in[6];
    const float* b_out = (const float*)d_in[7];
    const float* x0    = (const float*)d_in[8];
    const float* emb   = (const float*)d_in[9];
    float* out = (float*)d_out;

    char* ws = (char*)d_ws;
    f16*   Hh[2]  = { (f16*)(ws + ((size_t) 0 << 20)), (f16*)(ws + ((size_t)16 << 20)) };
    f16*   Hl[2]  = { (f16*)(ws + ((size_t) 8 << 20)), (f16*)(ws + ((size_t)24 << 20)) };
    f16*   Whr    = (f16*)(ws + ((size_t)32 << 20));
    f16*   Wlr    = (f16*)(ws + ((size_t)40 << 20));
    float* cbuf   = (float*)(ws + ((size_t)48 << 20));
    float* W_outT = (float*)(ws + ((size_t)64 << 20));
    float* rembT  = (float*)(ws + ((size_t)65 << 20));
    float* rembX0 = (float*)(ws + ((size_t)66 << 20));
    float* bR     = (float*)(ws + ((size_t)66 << 20) + 8192);
    float* XG     = (float*)(ws + ((size_t)67 << 20));
    int*   ambuf  = (int*)  (ws + ((size_t)69 << 20));

    float* out_msg0 = out;                                        // [L,B,V]
    float* out_mask = out + (size_t)MSGL * BATCH * VOC;           // [L,1,B]
    float* out_dig0 = out_mask + (size_t)MSGL * BATCH;            // [L,B,V]
    float* out_logp = out_dig0 + (size_t)MSGL * BATCH * VOC;      // [B]

    prep_w<<<4096, 256, 0, stream>>>(W_hh, Whr, Wlr);
    prep_h<<<4096, 256, 0, stream>>>(ench, Hh[0], Hl[0]);
    prep_c<<<4096, 256, 0, stream>>>(encc, cbuf);
    prep_small<<<256, 256, 0, stream>>>(W_out, b_ih, b_hh, emb, x0,
                                        W_outT, rembT, rembX0, bR, out_mask);
    xg_kernel<<<1024, 256, 0, stream>>>(W_ih, rembT, rembX0, bR, XG);

    for (int t = 0; t < MSGL; ++t) {
        const int cur = t & 1, nxt = cur ^ 1;
        gemm_fused<<<dim3(16, 16), 512, 0, stream>>>(
            Hh[cur], Hl[cur], Whr, Wlr, XG, ambuf, cbuf, Hh[nxt], Hl[nxt], t);
        logits_step<<<512, 256, 0, stream>>>(
            Hh[nxt], Hl[nxt], W_outT, b_out,
            out_msg0 + (size_t)t * BATCH * VOC,
            out_dig0 + (size_t)t * BATCH * VOC,
            out_logp, ambuf, t);
    }
}